// Round 1
// baseline (318.140 us; speedup 1.0000x reference)
//
#include <hip/hip_runtime.h>
#include <hip/hip_bf16.h>
#include <math.h>

typedef __bf16 bf16_t;
typedef __bf16 bf16x8 __attribute__((ext_vector_type(8)));
typedef float  f32x4  __attribute__((ext_vector_type(4)));

#define BB 8
#define CC 128
#define NN 4096
#define LDP 136                  // padded LDS row stride (bf16): 272B = 68 dwords -> 2-way (free)
#define SCALE 0.088388347648318447f   // 1/sqrt(128), folded into q

static __device__ __forceinline__ f32x4 mfma16(bf16x8 a, bf16x8 b, f32x4 c) {
    return __builtin_amdgcn_mfma_f32_16x16x32_bf16(a, b, c, 0, 0, 0);
}

// ---------------- K1a: GroupNorm stats (256 blocks = B*32 groups) ----------------
__global__ void __launch_bounds__(256) gn_stats(const float* __restrict__ in,
                                                float* __restrict__ stats) {
    int bg = blockIdx.x;                       // b*32 + g ; group = 4 channels = 16384 contiguous floats
    const float4* p4 = (const float4*)(in + (size_t)bg * 16384);
    int tid = threadIdx.x;
    float s = 0.f, ss = 0.f;
    for (int i = tid; i < 4096; i += 256) {
        float4 v = p4[i];
        s  += v.x + v.y + v.z + v.w;
        ss += v.x*v.x + v.y*v.y + v.z*v.z + v.w*v.w;
    }
    for (int off = 1; off < 64; off <<= 1) {
        s  += __shfl_xor(s,  off, 64);
        ss += __shfl_xor(ss, off, 64);
    }
    __shared__ float red[8];
    int wv = tid >> 6;
    if ((tid & 63) == 0) { red[wv*2] = s; red[wv*2+1] = ss; }
    __syncthreads();
    if (tid == 0) {
        float S  = red[0]+red[2]+red[4]+red[6];
        float SS = red[1]+red[3]+red[5]+red[7];
        float mu  = S * (1.f/16384.f);
        float var = SS * (1.f/16384.f) - mu*mu;
        stats[bg*2]   = mu;
        stats[bg*2+1] = rsqrtf(var + 1e-5f);
    }
}

// ---------------- K1b: normalize -> d_out (fp32 [B,C,N]) + x tokens (bf16 [B,N,C]) ----------------
__global__ void __launch_bounds__(256) gn_apply(const float* __restrict__ in,
                                                const float* __restrict__ gw,
                                                const float* __restrict__ gb,
                                                const float* __restrict__ stats,
                                                float* __restrict__ normed,
                                                bf16_t* __restrict__ x) {
    int b  = blockIdx.x >> 6;
    int p0 = (blockIdx.x & 63) << 6;           // 64 pixels per block
    int tid = threadIdx.x;
    __shared__ bf16_t tile[64 * 130];          // [pixel][channel], stride 130 (65 dw -> conflict-free)
    for (int i = tid; i < 8192; i += 256) {
        int c = i >> 6, p = i & 63;
        size_t idx = ((size_t)(b*CC + c)) * NN + p0 + p;
        float v = in[idx];
        int sg = b*32 + (c >> 2);
        float xn = (v - stats[sg*2]) * stats[sg*2+1] * gw[c] + gb[c];
        normed[idx] = xn;
        tile[p*130 + c] = (bf16_t)xn;
    }
    __syncthreads();
    bf16_t* xb = x + ((size_t)(b*NN + p0)) * CC;
    for (int i = tid; i < 4096; i += 256) {
        int p = i >> 6, cp = i & 63;
        unsigned int d = *(const unsigned int*)&tile[p*130 + cp*2];
        *(unsigned int*)&xb[p*CC + cp*2] = d;
    }
}

// ---------------- K2: q,k (bf16 [B,N,C], scale folded into q) and vT (bf16 [B,C,N]) ----------------
__global__ void __launch_bounds__(256) qkv_gemm(const bf16_t* __restrict__ x,
        const float* __restrict__ Wq, const float* __restrict__ bq,
        const float* __restrict__ Wk, const float* __restrict__ bk,
        const float* __restrict__ Wv, const float* __restrict__ bv,
        bf16_t* __restrict__ q, bf16_t* __restrict__ k, bf16_t* __restrict__ vT) {
    __shared__ bf16_t wb[CC * LDP];            // W tile bf16 (also reused as vT transpose buffer)
    int b  = blockIdx.x >> 5;
    int n0 = (blockIdx.x & 31) << 7;           // 128 rows per block
    int tid = threadIdx.x;
    int lane = tid & 63, l15 = lane & 15, quad = lane >> 4;
    int w = tid >> 6;                          // wave id: rows w*32 .. w*32+31 (2 row-tiles)
    // A fragments straight from global: 16B contiguous per lane
    bf16x8 afr[2][4];
    #pragma unroll
    for (int rt = 0; rt < 2; rt++)
        #pragma unroll
        for (int kb = 0; kb < 4; kb++)
            afr[rt][kb] = *(const bf16x8*)&x[(size_t)(b*NN + n0 + w*32 + rt*16 + l15)*CC + kb*32 + quad*8];

    const float* Ws[3] = {Wq, Wk, Wv};
    const float* bs[3] = {bq, bk, bv};
    for (int ph = 0; ph < 3; ph++) {
        __syncthreads();                       // protect wb from previous phase readers
        for (int i = tid; i < 2048; i += 256) {
            int row = i >> 4, s8 = i & 15;
            const float* wp = Ws[ph] + row*128 + s8*8;
            bf16x8 v;
            #pragma unroll
            for (int j = 0; j < 8; j++) v[j] = (bf16_t)wp[j];
            *(bf16x8*)&wb[row*LDP + s8*8] = v;
        }
        __syncthreads();
        f32x4 acc[2][8];
        f32x4 z = {0.f, 0.f, 0.f, 0.f};
        #pragma unroll
        for (int rt = 0; rt < 2; rt++)
            #pragma unroll
            for (int t = 0; t < 8; t++) acc[rt][t] = z;
        #pragma unroll
        for (int kb = 0; kb < 4; kb++)
            #pragma unroll
            for (int t = 0; t < 8; t++) {
                bf16x8 bf = *(const bf16x8*)&wb[(t*16 + l15)*LDP + kb*32 + quad*8];
                acc[0][t] = mfma16(afr[0][kb], bf, acc[0][t]);
                acc[1][t] = mfma16(afr[1][kb], bf, acc[1][t]);
            }
        if (ph < 2) {
            bf16_t* outp = (ph == 0) ? q : k;
            float sc = (ph == 0) ? SCALE : 1.0f;
            #pragma unroll
            for (int t = 0; t < 8; t++) {
                float bias = bs[ph][t*16 + l15];
                #pragma unroll
                for (int rt = 0; rt < 2; rt++)
                    #pragma unroll
                    for (int r = 0; r < 4; r++) {
                        int n = n0 + w*32 + rt*16 + quad*4 + r;
                        outp[(size_t)(b*NN + n)*CC + t*16 + l15] = (bf16_t)((acc[rt][t][r] + bias) * sc);
                    }
            }
        } else {
            __syncthreads();                   // all waves done reading wb
            #pragma unroll
            for (int t = 0; t < 8; t++) {
                float bias = bs[2][t*16 + l15];
                #pragma unroll
                for (int rt = 0; rt < 2; rt++)
                    #pragma unroll
                    for (int r = 0; r < 4; r++) {
                        int nloc = w*32 + rt*16 + quad*4 + r;   // vT transpose: [c][nloc]
                        wb[(t*16 + l15)*LDP + nloc] = (bf16_t)(acc[rt][t][r] + bias);
                    }
            }
            __syncthreads();
            for (int i = tid; i < 8192; i += 256) {
                int c = i >> 6, np = i & 63;
                unsigned int d = *(const unsigned int*)&wb[c*LDP + np*2];
                *(unsigned int*)&vT[(size_t)(b*CC + c)*NN + n0 + np*2] = d;
            }
        }
    }
}

// ---------------- K3: flash attention. Q-tile=64 (16 rows/wave), K-tile=128 ----------------
__global__ void __launch_bounds__(256) flash_attn(const bf16_t* __restrict__ q,
                                                  const bf16_t* __restrict__ k,
                                                  const bf16_t* __restrict__ vT,
                                                  bf16_t* __restrict__ ao) {
    __shared__ bf16_t kv[128 * LDP];           // shared k-tile then v-tile
    __shared__ bf16_t pb[4 * 16 * LDP];        // per-wave P region (no barrier needed)
    int b  = blockIdx.x >> 6;
    int q0 = (blockIdx.x & 63) << 6;
    int tid = threadIdx.x;
    int lane = tid & 63, l15 = lane & 15, quad = lane >> 4;
    int w = tid >> 6;
    bf16_t* pw = pb + w * 16 * LDP;

    bf16x8 qf[4];                              // q A-frags, loop invariant, direct from global
    #pragma unroll
    for (int kb = 0; kb < 4; kb++)
        qf[kb] = *(const bf16x8*)&q[(size_t)(b*NN + q0 + w*16 + l15)*CC + kb*32 + quad*8];

    f32x4 o[8];
    f32x4 z = {0.f, 0.f, 0.f, 0.f};
    #pragma unroll
    for (int t = 0; t < 8; t++) o[t] = z;
    float m_r[4], l_r[4];
    #pragma unroll
    for (int r = 0; r < 4; r++) { m_r[r] = -3.0e38f; l_r[r] = 0.f; }

    for (int j0 = 0; j0 < NN; j0 += 128) {
        __syncthreads();                       // prev PV done reading kv
        for (int i = tid; i < 2048; i += 256) {
            int row = i >> 4, seg = i & 15;
            *(bf16x8*)&kv[row*LDP + seg*8] =
                *(const bf16x8*)&k[(size_t)(b*NN + j0 + row)*CC + seg*8];
        }
        __syncthreads();
        // S = q @ k^T  (already scaled via q)
        f32x4 s[8];
        #pragma unroll
        for (int t = 0; t < 8; t++) s[t] = z;
        #pragma unroll
        for (int kb = 0; kb < 4; kb++)
            #pragma unroll
            for (int t = 0; t < 8; t++) {
                bf16x8 bf = *(const bf16x8*)&kv[(t*16 + l15)*LDP + kb*32 + quad*8];
                s[t] = mfma16(qf[kb], bf, s[t]);
            }
        // online softmax: lane owns rows quad*4+r, cols = 16 lanes of the quad-group
        float mloc[4];
        #pragma unroll
        for (int r = 0; r < 4; r++) {
            float v = s[0][r];
            #pragma unroll
            for (int t = 1; t < 8; t++) v = fmaxf(v, s[t][r]);
            mloc[r] = v;
        }
        for (int off = 1; off < 16; off <<= 1)
            #pragma unroll
            for (int r = 0; r < 4; r++) mloc[r] = fmaxf(mloc[r], __shfl_xor(mloc[r], off, 64));
        float al[4], rs[4];
        #pragma unroll
        for (int r = 0; r < 4; r++) {
            float mn = fmaxf(m_r[r], mloc[r]);
            al[r] = __expf(m_r[r] - mn);
            m_r[r] = mn;
            rs[r] = 0.f;
        }
        #pragma unroll
        for (int t = 0; t < 8; t++)
            #pragma unroll
            for (int r = 0; r < 4; r++) {
                float p = __expf(s[t][r] - m_r[r]);
                s[t][r] = p;
                rs[r] += p;
            }
        for (int off = 1; off < 16; off <<= 1)
            #pragma unroll
            for (int r = 0; r < 4; r++) rs[r] += __shfl_xor(rs[r], off, 64);
        #pragma unroll
        for (int r = 0; r < 4; r++) l_r[r] = l_r[r]*al[r] + rs[r];
        #pragma unroll
        for (int t = 0; t < 8; t++) {
            f32x4 ov = o[t];
            #pragma unroll
            for (int r = 0; r < 4; r++) ov[r] *= al[r];
            o[t] = ov;
        }
        // P -> per-wave LDS (C-layout -> A-layout transpose)
        #pragma unroll
        for (int t = 0; t < 8; t++)
            #pragma unroll
            for (int r = 0; r < 4; r++)
                pw[(quad*4 + r)*LDP + t*16 + l15] = (bf16_t)s[t][r];
        // stage v tile (vT rows are m-contiguous)
        __syncthreads();                       // all waves done reading k-tile
        for (int i = tid; i < 2048; i += 256) {
            int row = i >> 4, seg = i & 15;
            *(bf16x8*)&kv[row*LDP + seg*8] =
                *(const bf16x8*)&vT[(size_t)(b*CC + row)*NN + j0 + seg*8];
        }
        __syncthreads();
        // O += P @ V
        #pragma unroll
        for (int kb = 0; kb < 4; kb++) {
            bf16x8 ap = *(const bf16x8*)&pw[l15*LDP + kb*32 + quad*8];
            #pragma unroll
            for (int t = 0; t < 8; t++) {
                bf16x8 bf = *(const bf16x8*)&kv[(t*16 + l15)*LDP + kb*32 + quad*8];
                o[t] = mfma16(ap, bf, o[t]);
            }
        }
    }
    #pragma unroll
    for (int t = 0; t < 8; t++)
        #pragma unroll
        for (int r = 0; r < 4; r++) {
            int n = q0 + w*16 + quad*4 + r;
            ao[(size_t)(b*NN + n)*CC + t*16 + l15] = (bf16_t)(o[t][r] / l_r[r]);
        }
}

// ---------------- K4: proj GEMM + bias + transpose + residual into d_out ----------------
__global__ void __launch_bounds__(256) proj_out(const bf16_t* __restrict__ ao,
                                                const float* __restrict__ Wp,
                                                const float* __restrict__ bp,
                                                float* __restrict__ out) {
    __shared__ bf16_t wb[CC * LDP];
    int b  = blockIdx.x >> 5;
    int n0 = (blockIdx.x & 31) << 7;
    int tid = threadIdx.x;
    int lane = tid & 63, l15 = lane & 15, quad = lane >> 4;
    int w = tid >> 6;
    bf16x8 afr[2][4];
    #pragma unroll
    for (int rt = 0; rt < 2; rt++)
        #pragma unroll
        for (int kb = 0; kb < 4; kb++)
            afr[rt][kb] = *(const bf16x8*)&ao[(size_t)(b*NN + n0 + w*32 + rt*16 + l15)*CC + kb*32 + quad*8];
    for (int i = tid; i < 2048; i += 256) {
        int row = i >> 4, s8 = i & 15;
        const float* wp = Wp + row*128 + s8*8;
        bf16x8 v;
        #pragma unroll
        for (int j = 0; j < 8; j++) v[j] = (bf16_t)wp[j];
        *(bf16x8*)&wb[row*LDP + s8*8] = v;
    }
    __syncthreads();
    f32x4 acc[2][8];
    f32x4 z = {0.f, 0.f, 0.f, 0.f};
    #pragma unroll
    for (int rt = 0; rt < 2; rt++)
        #pragma unroll
        for (int t = 0; t < 8; t++) acc[rt][t] = z;
    #pragma unroll
    for (int kb = 0; kb < 4; kb++)
        #pragma unroll
        for (int t = 0; t < 8; t++) {
            bf16x8 bf = *(const bf16x8*)&wb[(t*16 + l15)*LDP + kb*32 + quad*8];
            acc[0][t] = mfma16(afr[0][kb], bf, acc[0][t]);
            acc[1][t] = mfma16(afr[1][kb], bf, acc[1][t]);
        }
    __syncthreads();
    #pragma unroll
    for (int t = 0; t < 8; t++) {
        float bias = bp[t*16 + l15];
        #pragma unroll
        for (int rt = 0; rt < 2; rt++)
            #pragma unroll
            for (int r = 0; r < 4; r++) {
                int nloc = w*32 + rt*16 + quad*4 + r;
                wb[(t*16 + l15)*LDP + nloc] = (bf16_t)(acc[rt][t][r] + bias);
            }
    }
    __syncthreads();
    for (int i = tid; i < 8192; i += 256) {
        int c = i >> 6, np = i & 63;
        bf16_t b0 = wb[c*LDP + np*2], b1 = wb[c*LDP + np*2 + 1];
        size_t idx = (size_t)(b*CC + c)*NN + n0 + np*2;
        float2 nv = *(float2*)&out[idx];
        nv.x += (float)b0;
        nv.y += (float)b1;
        *(float2*)&out[idx] = nv;
    }
}

extern "C" void kernel_launch(void* const* d_in, const int* in_sizes, int n_in,
                              void* d_out, int out_size, void* d_ws, size_t ws_size,
                              hipStream_t stream) {
    const float* in = (const float*)d_in[0];
    const float* gw = (const float*)d_in[1];
    const float* gb = (const float*)d_in[2];
    const float* Wq = (const float*)d_in[3];
    const float* bq = (const float*)d_in[4];
    const float* Wk = (const float*)d_in[5];
    const float* bk = (const float*)d_in[6];
    const float* Wv = (const float*)d_in[7];
    const float* bv = (const float*)d_in[8];
    const float* Wp = (const float*)d_in[9];
    const float* bp = (const float*)d_in[10];
    float* out = (float*)d_out;

    char* ws = (char*)d_ws;
    const size_t SZ = (size_t)BB * NN * CC * 2;   // 8.39 MB per bf16 buffer
    float*  stats = (float*)ws;                   // 2048 B
    bf16_t* x  = (bf16_t*)(ws + 2048);
    bf16_t* q  = (bf16_t*)(ws + 2048 + SZ);
    bf16_t* kk = (bf16_t*)(ws + 2048 + 2*SZ);
    bf16_t* vT = (bf16_t*)(ws + 2048 + 3*SZ);
    bf16_t* ao = (bf16_t*)(ws + 2048 + 4*SZ);

    gn_stats  <<<256, 256, 0, stream>>>(in, stats);
    gn_apply  <<<512, 256, 0, stream>>>(in, gw, gb, stats, out, x);
    qkv_gemm  <<<256, 256, 0, stream>>>(x, Wq, bq, Wk, bk, Wv, bv, q, kk, vT);
    flash_attn<<<512, 256, 0, stream>>>(q, kk, vT, ao);
    proj_out  <<<256, 256, 0, stream>>>(ao, Wp, bp, out);
}

// Round 2
// 266.408 us; speedup vs baseline: 1.1942x; 1.1942x over previous
//
#include <hip/hip_runtime.h>
#include <hip/hip_bf16.h>
#include <math.h>

typedef __bf16 bf16_t;
typedef __bf16 bf16x8 __attribute__((ext_vector_type(8)));
typedef float  f32x4  __attribute__((ext_vector_type(4)));
typedef float  f32x16 __attribute__((ext_vector_type(16)));

#define BB 8
#define CC 128
#define NN 4096
#define LDP 136                        // padded LDS stride for qkv/proj tiles
// 1/sqrt(128) * log2(e)  (attention scale folded into q, softmax in exp2 domain)
#define SCALE2 0.12751743342f

static __device__ __forceinline__ f32x4 mfma16(bf16x8 a, bf16x8 b, f32x4 c) {
    return __builtin_amdgcn_mfma_f32_16x16x32_bf16(a, b, c, 0, 0, 0);
}
static __device__ __forceinline__ f32x16 mfma32(bf16x8 a, bf16x8 b, f32x16 c) {
    return __builtin_amdgcn_mfma_f32_32x32x16_bf16(a, b, c, 0, 0, 0);
}
static __device__ __forceinline__ void gld16(const void* g, void* l) {
    __builtin_amdgcn_global_load_lds(
        (const __attribute__((address_space(1))) void*)g,
        (__attribute__((address_space(3))) void*)l, 16, 0, 0);
}
static __device__ __forceinline__ unsigned pack2bf(float a, float b) {
    union { bf16_t h[2]; unsigned u; } r;
    r.h[0] = (bf16_t)a; r.h[1] = (bf16_t)b;
    return r.u;
}

// ---------------- K1a: GroupNorm stats (256 blocks = B*32 groups) ----------------
__global__ void __launch_bounds__(256) gn_stats(const float* __restrict__ in,
                                                float* __restrict__ stats) {
    int bg = blockIdx.x;
    const float4* p4 = (const float4*)(in + (size_t)bg * 16384);
    int tid = threadIdx.x;
    float s = 0.f, ss = 0.f;
    for (int i = tid; i < 4096; i += 256) {
        float4 v = p4[i];
        s  += v.x + v.y + v.z + v.w;
        ss += v.x*v.x + v.y*v.y + v.z*v.z + v.w*v.w;
    }
    for (int off = 1; off < 64; off <<= 1) {
        s  += __shfl_xor(s,  off, 64);
        ss += __shfl_xor(ss, off, 64);
    }
    __shared__ float red[8];
    int wv = tid >> 6;
    if ((tid & 63) == 0) { red[wv*2] = s; red[wv*2+1] = ss; }
    __syncthreads();
    if (tid == 0) {
        float S  = red[0]+red[2]+red[4]+red[6];
        float SS = red[1]+red[3]+red[5]+red[7];
        float mu  = S * (1.f/16384.f);
        float var = SS * (1.f/16384.f) - mu*mu;
        stats[bg*2]   = mu;
        stats[bg*2+1] = rsqrtf(var + 1e-5f);
    }
}

// ---------------- K1b: normalize -> d_out (fp32 [B,C,N]) + x tokens (bf16 [B,N,C]) ----------------
__global__ void __launch_bounds__(256) gn_apply(const float* __restrict__ in,
                                                const float* __restrict__ gw,
                                                const float* __restrict__ gb,
                                                const float* __restrict__ stats,
                                                float* __restrict__ normed,
                                                bf16_t* __restrict__ x) {
    int b  = blockIdx.x >> 6;
    int p0 = (blockIdx.x & 63) << 6;
    int tid = threadIdx.x;
    __shared__ bf16_t tile[64 * 130];
    for (int i = tid; i < 8192; i += 256) {
        int c = i >> 6, p = i & 63;
        size_t idx = ((size_t)(b*CC + c)) * NN + p0 + p;
        float v = in[idx];
        int sg = b*32 + (c >> 2);
        float xn = (v - stats[sg*2]) * stats[sg*2+1] * gw[c] + gb[c];
        normed[idx] = xn;
        tile[p*130 + c] = (bf16_t)xn;
    }
    __syncthreads();
    bf16_t* xb = x + ((size_t)(b*NN + p0)) * CC;
    for (int i = tid; i < 4096; i += 256) {
        int p = i >> 6, cp = i & 63;
        unsigned int d = *(const unsigned int*)&tile[p*130 + cp*2];
        *(unsigned int*)&xb[p*CC + cp*2] = d;
    }
}

// ---------------- K2: q (plain, scaled), k (XOR-swizzled), vT (transposed + XOR-swizzled) ----------------
// Swizzle: within each row, 16B-group g stores logical group g ^ (row & 15).
__global__ void __launch_bounds__(256) qkv_gemm(const bf16_t* __restrict__ x,
        const float* __restrict__ Wq, const float* __restrict__ bq,
        const float* __restrict__ Wk, const float* __restrict__ bk,
        const float* __restrict__ Wv, const float* __restrict__ bv,
        bf16_t* __restrict__ q, bf16_t* __restrict__ k, bf16_t* __restrict__ vT) {
    __shared__ bf16_t wb[CC * LDP];
    int b  = blockIdx.x >> 5;
    int n0 = (blockIdx.x & 31) << 7;
    int tid = threadIdx.x;
    int lane = tid & 63, l15 = lane & 15, quad = lane >> 4;
    int w = tid >> 6;
    bf16x8 afr[2][4];
    #pragma unroll
    for (int rt = 0; rt < 2; rt++)
        #pragma unroll
        for (int kb = 0; kb < 4; kb++)
            afr[rt][kb] = *(const bf16x8*)&x[(size_t)(b*NN + n0 + w*32 + rt*16 + l15)*CC + kb*32 + quad*8];

    const float* Ws[3] = {Wq, Wk, Wv};
    const float* bs[3] = {bq, bk, bv};
    for (int ph = 0; ph < 3; ph++) {
        __syncthreads();
        for (int i = tid; i < 2048; i += 256) {
            int row = i >> 4, s8 = i & 15;
            const float* wp = Ws[ph] + row*128 + s8*8;
            bf16x8 v;
            #pragma unroll
            for (int j = 0; j < 8; j++) v[j] = (bf16_t)wp[j];
            *(bf16x8*)&wb[row*LDP + s8*8] = v;
        }
        __syncthreads();
        f32x4 acc[2][8];
        f32x4 z = {0.f, 0.f, 0.f, 0.f};
        #pragma unroll
        for (int rt = 0; rt < 2; rt++)
            #pragma unroll
            for (int t = 0; t < 8; t++) acc[rt][t] = z;
        #pragma unroll
        for (int kb = 0; kb < 4; kb++)
            #pragma unroll
            for (int t = 0; t < 8; t++) {
                bf16x8 bf = *(const bf16x8*)&wb[(t*16 + l15)*LDP + kb*32 + quad*8];
                acc[0][t] = mfma16(afr[0][kb], bf, acc[0][t]);
                acc[1][t] = mfma16(afr[1][kb], bf, acc[1][t]);
            }
        if (ph == 0) {
            #pragma unroll
            for (int t = 0; t < 8; t++) {
                float bias = bs[0][t*16 + l15];
                #pragma unroll
                for (int rt = 0; rt < 2; rt++)
                    #pragma unroll
                    for (int r = 0; r < 4; r++) {
                        int n = n0 + w*32 + rt*16 + quad*4 + r;
                        q[(size_t)(b*NN + n)*CC + t*16 + l15] = (bf16_t)((acc[rt][t][r] + bias) * SCALE2);
                    }
            }
        } else if (ph == 1) {
            #pragma unroll
            for (int t = 0; t < 8; t++) {
                float bias = bs[1][t*16 + l15];
                #pragma unroll
                for (int rt = 0; rt < 2; rt++)
                    #pragma unroll
                    for (int r = 0; r < 4; r++) {
                        int n = n0 + w*32 + rt*16 + quad*4 + r;
                        int sw = (2*t + (l15 >> 3)) ^ (quad*4 + r);   // (n&15) == quad*4+r
                        k[(size_t)(b*NN + n)*CC + sw*8 + (l15 & 7)] = (bf16_t)(acc[rt][t][r] + bias);
                    }
            }
        } else {
            __syncthreads();
            #pragma unroll
            for (int t = 0; t < 8; t++) {
                float bias = bs[2][t*16 + l15];
                #pragma unroll
                for (int rt = 0; rt < 2; rt++)
                    #pragma unroll
                    for (int r = 0; r < 4; r++) {
                        int nloc = w*32 + rt*16 + quad*4 + r;
                        wb[(t*16 + l15)*LDP + nloc] = (bf16_t)(acc[rt][t][r] + bias);
                    }
            }
            __syncthreads();
            for (int i = tid; i < 8192; i += 256) {
                int c = i >> 6, np = i & 63;
                unsigned int d = *(const unsigned int*)&wb[c*LDP + np*2];
                *(unsigned int*)&vT[(size_t)(b*CC + c)*NN + n0 + (((np >> 2) ^ (c & 15)) << 3) + ((np & 3) << 1)] = d;
            }
        }
    }
}

// ---------------- K3: flash attention, 32x32x16 MFMA, S^T trick, dbuf global_load_lds ----------------
// grid 256: b = blk>>5, q0 = (blk&31)*128. 4 waves x 32 q-rows.
__global__ void __launch_bounds__(256, 1) flash_attn(const bf16_t* __restrict__ qg,
                                                     const bf16_t* __restrict__ kg,
                                                     const bf16_t* __restrict__ vg,
                                                     bf16_t* __restrict__ ao) {
    __shared__ bf16_t kbuf[2][128*128];   // 64 KB (XOR-swizzled rows, straight copy of global)
    __shared__ bf16_t vbuf[2][128*128];   // 64 KB
    const int b    = blockIdx.x >> 5;
    const int q0   = (blockIdx.x & 31) << 7;
    const int tid  = threadIdx.x;
    const int lane = tid & 63;
    const int l31  = lane & 31;
    const int h    = lane >> 5;
    const int w    = tid >> 6;

    // q B-frags: lane holds Q[q0+w*32+l31][kc*16 + h*8 + e]  (same mapping as A-frag)
    bf16x8 qf[8];
    {
        const bf16_t* qr = qg + ((size_t)(b*NN + q0 + w*32 + l31))*CC + h*8;
        #pragma unroll
        for (int kc = 0; kc < 8; kc++) qf[kc] = *(const bf16x8*)(qr + kc*16);
    }

    f32x16 ot[4];   // O^T accumulator: lane holds O^T[chan][qrow=l31]
    #pragma unroll
    for (int ct = 0; ct < 4; ct++)
        #pragma unroll
        for (int r = 0; r < 16; r++) ot[ct][r] = 0.f;
    float m = -3.0e38f, l = 0.f;

    // stage tile 0 (k and v tiles are straight 32KB copies; swizzle pre-applied in global)
    {
        const bf16_t* kt = kg + ((size_t)(b*NN))*CC;
        #pragma unroll
        for (int it = 0; it < 8; it++) {
            int cb = it*256 + w*64;
            gld16(kt + (size_t)(cb + lane)*8, &kbuf[0][cb*8]);
        }
        #pragma unroll
        for (int it = 0; it < 8; it++) {
            int cb = it*256 + w*64;
            int c = cb + lane;
            gld16(vg + ((size_t)(b*CC + (c >> 4)))*NN + (c & 15)*8, &vbuf[0][cb*8]);
        }
    }
    __syncthreads();

    for (int i = 0; i < 32; i++) {
        const int cur = i & 1;
        if (i < 31) {   // prefetch next tile into the other buffer (drained by end barrier)
            const int j0n = (i + 1) << 7;
            const bf16_t* kt = kg + ((size_t)(b*NN + j0n))*CC;
            #pragma unroll
            for (int it = 0; it < 8; it++) {
                int cb = it*256 + w*64;
                gld16(kt + (size_t)(cb + lane)*8, &kbuf[cur^1][cb*8]);
            }
            #pragma unroll
            for (int it = 0; it < 8; it++) {
                int cb = it*256 + w*64;
                int c = cb + lane;
                gld16(vg + ((size_t)(b*CC + (c >> 4)))*NN + j0n + (c & 15)*8, &vbuf[cur^1][cb*8]);
            }
        }
        // S^T = K_tile · Q^T : lane holds S^T[j = tt*32 + (r&3)+8*(r>>2)+4h][qrow = l31]
        f32x16 st[4];
        #pragma unroll
        for (int tt = 0; tt < 4; tt++)
            #pragma unroll
            for (int r = 0; r < 16; r++) st[tt][r] = 0.f;
        #pragma unroll
        for (int tt = 0; tt < 4; tt++)
            #pragma unroll
            for (int kc = 0; kc < 8; kc++) {
                bf16x8 kf = *(const bf16x8*)&kbuf[cur][(tt*32 + l31)*128 + (((2*kc + h) ^ (l31 & 15)) << 3)];
                st[tt] = mfma32(kf, qf[kc], st[tt]);
            }
        // online softmax: per-lane state for q-row l31 (this lane: 64 of 128 cols; partner lane^32 has the rest)
        float mx = st[0][0];
        #pragma unroll
        for (int tt = 0; tt < 4; tt++)
            #pragma unroll
            for (int r = 0; r < 16; r++) mx = fmaxf(mx, st[tt][r]);
        mx = fmaxf(mx, __shfl_xor(mx, 32, 64));
        float mn = fmaxf(m, mx);
        float al = exp2f(m - mn);
        m = mn;
        float sum = 0.f;
        #pragma unroll
        for (int tt = 0; tt < 4; tt++)
            #pragma unroll
            for (int r = 0; r < 16; r++) {
                float p = exp2f(st[tt][r] - mn);
                st[tt][r] = p;
                sum += p;
            }
        sum += __shfl_xor(sum, 32, 64);
        l = l * al + sum;
        #pragma unroll
        for (int ct = 0; ct < 4; ct++)
            #pragma unroll
            for (int r = 0; r < 16; r++) ot[ct][r] *= al;
        // O^T += V^T · P^T.  P^T B-frag needs lane^32 exchange only:
        // frag e0-3 come from h'=0 source, e4-7 from h'=1; src reg group g = 2*(kc&1) + h_dst.
        #pragma unroll
        for (int tt = 0; tt < 4; tt++) {
            unsigned pk0[4], pk1[4];
            #pragma unroll
            for (int g = 0; g < 4; g++) {
                pk0[g] = pack2bf(st[tt][4*g],     st[tt][4*g + 1]);
                pk1[g] = pack2bf(st[tt][4*g + 2], st[tt][4*g + 3]);
            }
            #pragma unroll
            for (int kh = 0; kh < 2; kh++) {
                const int kc = tt*2 + kh;
                unsigned pay0 = h ? pk0[2*kh]     : pk0[2*kh + 1];   // what my xor-partner needs
                unsigned pay1 = h ? pk1[2*kh]     : pk1[2*kh + 1];
                unsigned loc0 = h ? pk0[2*kh + 1] : pk0[2*kh];       // my own group
                unsigned loc1 = h ? pk1[2*kh + 1] : pk1[2*kh];
                unsigned r0 = (unsigned)__shfl_xor((int)pay0, 32, 64);
                unsigned r1 = (unsigned)__shfl_xor((int)pay1, 32, 64);
                union { unsigned u[4]; bf16x8 v; } pf;
                pf.u[0] = h ? r0 : loc0;
                pf.u[1] = h ? r1 : loc1;
                pf.u[2] = h ? loc0 : r0;
                pf.u[3] = h ? loc1 : r1;
                #pragma unroll
                for (int ct = 0; ct < 4; ct++) {
                    bf16x8 vf = *(const bf16x8*)&vbuf[cur][(ct*32 + l31)*128 + (((2*kc + h) ^ (l31 & 15)) << 3)];
                    ot[ct] = mfma32(vf, pf.v, ot[ct]);
                }
            }
        }
        __syncthreads();
    }
    // epilogue: O^T[chan][qrow=l31] -> ao[qrow][chan]
    float rl = 1.0f / l;
    const size_t obase = ((size_t)(b*NN + q0 + w*32 + l31))*CC;
    #pragma unroll
    for (int ct = 0; ct < 4; ct++)
        #pragma unroll
        for (int r = 0; r < 16; r++) {
            int chan = ct*32 + (r & 3) + ((r >> 2) << 3) + 4*h;
            ao[obase + chan] = (bf16_t)(ot[ct][r] * rl);
        }
}

// ---------------- K4: proj GEMM + bias + transpose + residual into d_out ----------------
__global__ void __launch_bounds__(256) proj_out(const bf16_t* __restrict__ ao,
                                                const float* __restrict__ Wp,
                                                const float* __restrict__ bp,
                                                float* __restrict__ out) {
    __shared__ bf16_t wb[CC * LDP];
    int b  = blockIdx.x >> 5;
    int n0 = (blockIdx.x & 31) << 7;
    int tid = threadIdx.x;
    int lane = tid & 63, l15 = lane & 15, quad = lane >> 4;
    int w = tid >> 6;
    bf16x8 afr[2][4];
    #pragma unroll
    for (int rt = 0; rt < 2; rt++)
        #pragma unroll
        for (int kb = 0; kb < 4; kb++)
            afr[rt][kb] = *(const bf16x8*)&ao[(size_t)(b*NN + n0 + w*32 + rt*16 + l15)*CC + kb*32 + quad*8];
    for (int i = tid; i < 2048; i += 256) {
        int row = i >> 4, s8 = i & 15;
        const float* wp = Wp + row*128 + s8*8;
        bf16x8 v;
        #pragma unroll
        for (int j = 0; j < 8; j++) v[j] = (bf16_t)wp[j];
        *(bf16x8*)&wb[row*LDP + s8*8] = v;
    }
    __syncthreads();
    f32x4 acc[2][8];
    f32x4 z = {0.f, 0.f, 0.f, 0.f};
    #pragma unroll
    for (int rt = 0; rt < 2; rt++)
        #pragma unroll
        for (int t = 0; t < 8; t++) acc[rt][t] = z;
    #pragma unroll
    for (int kb = 0; kb < 4; kb++)
        #pragma unroll
        for (int t = 0; t < 8; t++) {
            bf16x8 bf = *(const bf16x8*)&wb[(t*16 + l15)*LDP + kb*32 + quad*8];
            acc[0][t] = mfma16(afr[0][kb], bf, acc[0][t]);
            acc[1][t] = mfma16(afr[1][kb], bf, acc[1][t]);
        }
    __syncthreads();
    #pragma unroll
    for (int t = 0; t < 8; t++) {
        float bias = bp[t*16 + l15];
        #pragma unroll
        for (int rt = 0; rt < 2; rt++)
            #pragma unroll
            for (int r = 0; r < 4; r++) {
                int nloc = w*32 + rt*16 + quad*4 + r;
                wb[(t*16 + l15)*LDP + nloc] = (bf16_t)(acc[rt][t][r] + bias);
            }
    }
    __syncthreads();
    for (int i = tid; i < 8192; i += 256) {
        int c = i >> 6, np = i & 63;
        bf16_t b0 = wb[c*LDP + np*2], b1 = wb[c*LDP + np*2 + 1];
        size_t idx = (size_t)(b*CC + c)*NN + n0 + np*2;
        float2 nv = *(float2*)&out[idx];
        nv.x += (float)b0;
        nv.y += (float)b1;
        *(float2*)&out[idx] = nv;
    }
}

extern "C" void kernel_launch(void* const* d_in, const int* in_sizes, int n_in,
                              void* d_out, int out_size, void* d_ws, size_t ws_size,
                              hipStream_t stream) {
    const float* in = (const float*)d_in[0];
    const float* gw = (const float*)d_in[1];
    const float* gb = (const float*)d_in[2];
    const float* Wq = (const float*)d_in[3];
    const float* bq = (const float*)d_in[4];
    const float* Wk = (const float*)d_in[5];
    const float* bk = (const float*)d_in[6];
    const float* Wv = (const float*)d_in[7];
    const float* bv = (const float*)d_in[8];
    const float* Wp = (const float*)d_in[9];
    const float* bp = (const float*)d_in[10];
    float* out = (float*)d_out;

    char* ws = (char*)d_ws;
    const size_t SZ = (size_t)BB * NN * CC * 2;
    float*  stats = (float*)ws;
    bf16_t* x  = (bf16_t*)(ws + 2048);
    bf16_t* q  = (bf16_t*)(ws + 2048 + SZ);
    bf16_t* kk = (bf16_t*)(ws + 2048 + 2*SZ);
    bf16_t* vT = (bf16_t*)(ws + 2048 + 3*SZ);
    bf16_t* ao = (bf16_t*)(ws + 2048 + 4*SZ);

    gn_stats  <<<256, 256, 0, stream>>>(in, stats);
    gn_apply  <<<512, 256, 0, stream>>>(in, gw, gb, stats, out, x);
    qkv_gemm  <<<256, 256, 0, stream>>>(x, Wq, bq, Wk, bk, Wv, bv, q, kk, vT);
    flash_attn<<<256, 256, 0, stream>>>(q, kk, vT, ao);
    proj_out  <<<256, 256, 0, stream>>>(ao, Wp, bp, out);
}

// Round 3
// 238.648 us; speedup vs baseline: 1.3331x; 1.1163x over previous
//
#include <hip/hip_runtime.h>
#include <hip/hip_bf16.h>
#include <math.h>

typedef __bf16 bf16_t;
typedef __bf16 bf16x8 __attribute__((ext_vector_type(8)));
typedef float  f32x4  __attribute__((ext_vector_type(4)));
typedef float  f32x16 __attribute__((ext_vector_type(16)));

#define BB 8
#define CC 128
#define NN 4096
#define LDP 136
// 1/sqrt(128) * log2(e)  (attention scale folded into q, softmax in exp2 domain)
#define SCALE2 0.12751743342f

static __device__ __forceinline__ f32x4 mfma16(bf16x8 a, bf16x8 b, f32x4 c) {
    return __builtin_amdgcn_mfma_f32_16x16x32_bf16(a, b, c, 0, 0, 0);
}
static __device__ __forceinline__ f32x16 mfma32(bf16x8 a, bf16x8 b, f32x16 c) {
    return __builtin_amdgcn_mfma_f32_32x32x16_bf16(a, b, c, 0, 0, 0);
}
static __device__ __forceinline__ void gld16(const void* g, void* l) {
    __builtin_amdgcn_global_load_lds(
        (const __attribute__((address_space(1))) void*)g,
        (__attribute__((address_space(3))) void*)l, 16, 0, 0);
}
static __device__ __forceinline__ unsigned pack2bf(float a, float b) {
    union { bf16_t h[2]; unsigned u; } r;
    r.h[0] = (bf16_t)a; r.h[1] = (bf16_t)b;
    return r.u;
}

// ---------------- K1a: GroupNorm stats ----------------
__global__ void __launch_bounds__(256) gn_stats(const float* __restrict__ in,
                                                float* __restrict__ stats) {
    int bg = blockIdx.x;
    const float4* p4 = (const float4*)(in + (size_t)bg * 16384);
    int tid = threadIdx.x;
    float s = 0.f, ss = 0.f;
    for (int i = tid; i < 4096; i += 256) {
        float4 v = p4[i];
        s  += v.x + v.y + v.z + v.w;
        ss += v.x*v.x + v.y*v.y + v.z*v.z + v.w*v.w;
    }
    for (int off = 1; off < 64; off <<= 1) {
        s  += __shfl_xor(s,  off, 64);
        ss += __shfl_xor(ss, off, 64);
    }
    __shared__ float red[8];
    int wv = tid >> 6;
    if ((tid & 63) == 0) { red[wv*2] = s; red[wv*2+1] = ss; }
    __syncthreads();
    if (tid == 0) {
        float S  = red[0]+red[2]+red[4]+red[6];
        float SS = red[1]+red[3]+red[5]+red[7];
        float mu  = S * (1.f/16384.f);
        float var = SS * (1.f/16384.f) - mu*mu;
        stats[bg*2]   = mu;
        stats[bg*2+1] = rsqrtf(var + 1e-5f);
    }
}

// ---------------- K1b: normalize -> d_out (fp32) + x tokens (bf16 [B,N,C]) ----------------
__global__ void __launch_bounds__(256) gn_apply(const float* __restrict__ in,
                                                const float* __restrict__ gw,
                                                const float* __restrict__ gb,
                                                const float* __restrict__ stats,
                                                float* __restrict__ normed,
                                                bf16_t* __restrict__ x) {
    int b  = blockIdx.x >> 6;
    int p0 = (blockIdx.x & 63) << 6;
    int tid = threadIdx.x;
    __shared__ bf16_t tile[64 * 130];
    for (int i = tid; i < 8192; i += 256) {
        int c = i >> 6, p = i & 63;
        size_t idx = ((size_t)(b*CC + c)) * NN + p0 + p;
        float v = in[idx];
        int sg = b*32 + (c >> 2);
        float xn = (v - stats[sg*2]) * stats[sg*2+1] * gw[c] + gb[c];
        normed[idx] = xn;
        tile[p*130 + c] = (bf16_t)xn;
    }
    __syncthreads();
    bf16_t* xb = x + ((size_t)(b*NN + p0)) * CC;
    for (int i = tid; i < 4096; i += 256) {
        int p = i >> 6, cp = i & 63;
        unsigned int d = *(const unsigned int*)&tile[p*130 + cp*2];
        *(unsigned int*)&xb[p*CC + cp*2] = d;
    }
}

// ---------------- K2: q (scaled), k (XOR-swizzled), vT (transposed + bit2<->3 perm + XOR-swizzled) ----
__global__ void __launch_bounds__(256) qkv_gemm(const bf16_t* __restrict__ x,
        const float* __restrict__ Wq, const float* __restrict__ bq,
        const float* __restrict__ Wk, const float* __restrict__ bk,
        const float* __restrict__ Wv, const float* __restrict__ bv,
        bf16_t* __restrict__ q, bf16_t* __restrict__ k, bf16_t* __restrict__ vT) {
    __shared__ bf16_t wb[CC * LDP];
    int b  = blockIdx.x >> 5;
    int n0 = (blockIdx.x & 31) << 7;
    int tid = threadIdx.x;
    int lane = tid & 63, l15 = lane & 15, quad = lane >> 4;
    int w = tid >> 6;
    bf16x8 afr[2][4];
    #pragma unroll
    for (int rt = 0; rt < 2; rt++)
        #pragma unroll
        for (int kb = 0; kb < 4; kb++)
            afr[rt][kb] = *(const bf16x8*)&x[(size_t)(b*NN + n0 + w*32 + rt*16 + l15)*CC + kb*32 + quad*8];

    const float* Ws[3] = {Wq, Wk, Wv};
    const float* bs[3] = {bq, bk, bv};
    for (int ph = 0; ph < 3; ph++) {
        __syncthreads();
        for (int i = tid; i < 2048; i += 256) {
            int row = i >> 4, s8 = i & 15;
            const float* wp = Ws[ph] + row*128 + s8*8;
            bf16x8 v;
            #pragma unroll
            for (int j = 0; j < 8; j++) v[j] = (bf16_t)wp[j];
            *(bf16x8*)&wb[row*LDP + s8*8] = v;
        }
        __syncthreads();
        f32x4 acc[2][8];
        f32x4 z = {0.f, 0.f, 0.f, 0.f};
        #pragma unroll
        for (int rt = 0; rt < 2; rt++)
            #pragma unroll
            for (int t = 0; t < 8; t++) acc[rt][t] = z;
        #pragma unroll
        for (int kb = 0; kb < 4; kb++)
            #pragma unroll
            for (int t = 0; t < 8; t++) {
                bf16x8 bf = *(const bf16x8*)&wb[(t*16 + l15)*LDP + kb*32 + quad*8];
                acc[0][t] = mfma16(afr[0][kb], bf, acc[0][t]);
                acc[1][t] = mfma16(afr[1][kb], bf, acc[1][t]);
            }
        __syncthreads();   // all waves done reading W from wb
        if (ph < 2) {
            float sc = (ph == 0) ? SCALE2 : 1.0f;
            #pragma unroll
            for (int t = 0; t < 8; t++) {
                float bias = bs[ph][t*16 + l15];
                #pragma unroll
                for (int rt = 0; rt < 2; rt++)
                    #pragma unroll
                    for (int r = 0; r < 4; r++) {
                        int nloc = w*32 + rt*16 + quad*4 + r;
                        wb[nloc*LDP + t*16 + l15] = (bf16_t)((acc[rt][t][r] + bias) * sc);
                    }
            }
            __syncthreads();
            bf16_t* outp = (ph == 0) ? q : k;
            for (int i = tid; i < 2048; i += 256) {
                int row = i >> 4, g = i & 15;
                bf16x8 vv = *(const bf16x8*)&wb[row*LDP + g*8];
                int gd = (ph == 0) ? g : (g ^ (row & 15));
                *(bf16x8*)&outp[(size_t)(b*NN + n0 + row)*CC + gd*8] = vv;
            }
        } else {
            #pragma unroll
            for (int t = 0; t < 8; t++) {
                float bias = bs[2][t*16 + l15];
                #pragma unroll
                for (int rt = 0; rt < 2; rt++)
                    #pragma unroll
                    for (int r = 0; r < 4; r++) {
                        int nloc = w*32 + rt*16 + quad*4 + r;   // vT transpose: [c][nloc]
                        wb[(t*16 + l15)*LDP + nloc] = (bf16_t)(acc[rt][t][r] + bias);
                    }
            }
            __syncthreads();
            for (int i = tid; i < 8192; i += 256) {
                int c = i >> 6, np = i & 63;   // np = pair index (n = 2*np)
                unsigned int d = *(const unsigned int*)&wb[c*LDP + np*2];
                // bit2<->3 swap of n == bit1<->2 swap of np (PV B-frag identity perm)
                int npp = (np & ~6) | ((np & 2) << 1) | ((np & 4) >> 1);
                int g = (npp >> 2) ^ (c & 15);            // XOR bank swizzle on 8-elem groups
                *(unsigned int*)&vT[(size_t)(b*CC + c)*NN + n0 + (g << 3) + ((npp & 3) << 1)] = d;
            }
        }
    }
}

// ---------------- K3: flash attention, 32x32x16, S^T trick, exchange-free PV ----------------
__global__ void __launch_bounds__(256, 1) flash_attn(const bf16_t* __restrict__ qg,
                                                     const bf16_t* __restrict__ kg,
                                                     const bf16_t* __restrict__ vg,
                                                     bf16_t* __restrict__ ao) {
    __shared__ bf16_t kbuf[2][128*128];
    __shared__ bf16_t vbuf[2][128*128];
    const int b    = blockIdx.x >> 5;
    const int q0   = (blockIdx.x & 31) << 7;
    const int tid  = threadIdx.x;
    const int lane = tid & 63;
    const int l31  = lane & 31;
    const int h    = lane >> 5;
    const int w    = tid >> 6;

    bf16x8 qf[8];
    {
        const bf16_t* qr = qg + ((size_t)(b*NN + q0 + w*32 + l31))*CC + h*8;
        #pragma unroll
        for (int kc = 0; kc < 8; kc++) qf[kc] = *(const bf16x8*)(qr + kc*16);
    }
    // per-kc swizzled group byte offsets (loop-invariant)
    int gofs[8];
    #pragma unroll
    for (int kc = 0; kc < 8; kc++) gofs[kc] = ((2*kc + h) ^ (l31 & 15)) << 3;

    f32x16 ot[4];
    #pragma unroll
    for (int ct = 0; ct < 4; ct++)
        #pragma unroll
        for (int r = 0; r < 16; r++) ot[ct][r] = 0.f;
    float m = -3.0e38f, l = 0.f;

    {
        const bf16_t* kt = kg + ((size_t)(b*NN))*CC;
        #pragma unroll
        for (int it = 0; it < 8; it++) {
            int cb = it*256 + w*64;
            gld16(kt + (size_t)(cb + lane)*8, &kbuf[0][cb*8]);
        }
        #pragma unroll
        for (int it = 0; it < 8; it++) {
            int cb = it*256 + w*64;
            int c = cb + lane;
            gld16(vg + ((size_t)(b*CC + (c >> 4)))*NN + (c & 15)*8, &vbuf[0][cb*8]);
        }
    }
    __syncthreads();

    for (int i = 0; i < 32; i++) {
        const int cur = i & 1;
        if (i < 31) {
            const int j0n = (i + 1) << 7;
            const bf16_t* kt = kg + ((size_t)(b*NN + j0n))*CC;
            #pragma unroll
            for (int it = 0; it < 8; it++) {
                int cb = it*256 + w*64;
                gld16(kt + (size_t)(cb + lane)*8, &kbuf[cur^1][cb*8]);
            }
            #pragma unroll
            for (int it = 0; it < 8; it++) {
                int cb = it*256 + w*64;
                int c = cb + lane;
                gld16(vg + ((size_t)(b*CC + (c >> 4)))*NN + j0n + (c & 15)*8, &vbuf[cur^1][cb*8]);
            }
        }
        // S^T = K_tile . Q^T
        f32x16 st[4];
        #pragma unroll
        for (int tt = 0; tt < 4; tt++)
            #pragma unroll
            for (int r = 0; r < 16; r++) st[tt][r] = 0.f;
        #pragma unroll
        for (int tt = 0; tt < 4; tt++) {
            const bf16_t* krow = &kbuf[cur][(tt*32 + l31)*128];
            #pragma unroll
            for (int kc = 0; kc < 8; kc++) {
                bf16x8 kf = *(const bf16x8*)(krow + gofs[kc]);
                st[tt] = mfma32(kf, qf[kc], st[tt]);
            }
        }
        // online softmax (per-lane state, partner lane^32 holds other 64 cols)
        float mtt[4];
        #pragma unroll
        for (int tt = 0; tt < 4; tt++) {
            float b0 = fmaxf(fmaxf(st[tt][0],  st[tt][1]),  fmaxf(st[tt][2],  st[tt][3]));
            float b1 = fmaxf(fmaxf(st[tt][4],  st[tt][5]),  fmaxf(st[tt][6],  st[tt][7]));
            float b2 = fmaxf(fmaxf(st[tt][8],  st[tt][9]),  fmaxf(st[tt][10], st[tt][11]));
            float b3 = fmaxf(fmaxf(st[tt][12], st[tt][13]), fmaxf(st[tt][14], st[tt][15]));
            mtt[tt] = fmaxf(fmaxf(b0, b1), fmaxf(b2, b3));
        }
        float mx = fmaxf(fmaxf(mtt[0], mtt[1]), fmaxf(mtt[2], mtt[3]));
        mx = fmaxf(mx, __shfl_xor(mx, 32, 64));
        float mn = fmaxf(m, mx);
        float al = __builtin_amdgcn_exp2f(m - mn);
        m = mn;
        float stt[4];
        #pragma unroll
        for (int tt = 0; tt < 4; tt++) {
            #pragma unroll
            for (int r = 0; r < 16; r++)
                st[tt][r] = __builtin_amdgcn_exp2f(st[tt][r] - mn);
            float b0 = (st[tt][0]  + st[tt][1])  + (st[tt][2]  + st[tt][3]);
            float b1 = (st[tt][4]  + st[tt][5])  + (st[tt][6]  + st[tt][7]);
            float b2 = (st[tt][8]  + st[tt][9])  + (st[tt][10] + st[tt][11]);
            float b3 = (st[tt][12] + st[tt][13]) + (st[tt][14] + st[tt][15]);
            stt[tt] = (b0 + b1) + (b2 + b3);
        }
        float sum = (stt[0] + stt[1]) + (stt[2] + stt[3]);
        sum += __shfl_xor(sum, 32, 64);
        l = l * al + sum;
        #pragma unroll
        for (int ct = 0; ct < 4; ct++)
            #pragma unroll
            for (int r = 0; r < 16; r++) ot[ct][r] *= al;
        // O^T += V^T . P^T  — exchange-free: B-frag e = st[tt][8*kcl + e]
        #pragma unroll
        for (int tt = 0; tt < 4; tt++)
            #pragma unroll
            for (int kcl = 0; kcl < 2; kcl++) {
                const int kc = tt*2 + kcl;
                union { unsigned u[4]; bf16x8 v; } pf;
                #pragma unroll
                for (int g = 0; g < 4; g++)
                    pf.u[g] = pack2bf(st[tt][8*kcl + 2*g], st[tt][8*kcl + 2*g + 1]);
                #pragma unroll
                for (int ct = 0; ct < 4; ct++) {
                    bf16x8 vf = *(const bf16x8*)&vbuf[cur][(ct*32 + l31)*128 + gofs[kc]];
                    ot[ct] = mfma32(vf, pf.v, ot[ct]);
                }
            }
        __syncthreads();
    }
    // epilogue: O^T[chan][qrow=l31] -> ao[qrow][chan], packed b64 stores
    float rl = 1.0f / l;
    bf16_t* orow = ao + ((size_t)(b*NN + q0 + w*32 + l31))*CC;
    #pragma unroll
    for (int ct = 0; ct < 4; ct++)
        #pragma unroll
        for (int g = 0; g < 4; g++) {
            unsigned p0 = pack2bf(ot[ct][4*g]   * rl, ot[ct][4*g+1] * rl);
            unsigned p1 = pack2bf(ot[ct][4*g+2] * rl, ot[ct][4*g+3] * rl);
            union { unsigned u[2]; unsigned long long ll; } pk;
            pk.u[0] = p0; pk.u[1] = p1;
            *(unsigned long long*)&orow[ct*32 + g*8 + 4*h] = pk.ll;
        }
}

// ---------------- K4: proj GEMM + bias + transpose + residual into d_out ----------------
__global__ void __launch_bounds__(256) proj_out(const bf16_t* __restrict__ ao,
                                                const float* __restrict__ Wp,
                                                const float* __restrict__ bp,
                                                float* __restrict__ out) {
    __shared__ bf16_t wb[CC * LDP];
    int b  = blockIdx.x >> 5;
    int n0 = (blockIdx.x & 31) << 7;
    int tid = threadIdx.x;
    int lane = tid & 63, l15 = lane & 15, quad = lane >> 4;
    int w = tid >> 6;
    bf16x8 afr[2][4];
    #pragma unroll
    for (int rt = 0; rt < 2; rt++)
        #pragma unroll
        for (int kb = 0; kb < 4; kb++)
            afr[rt][kb] = *(const bf16x8*)&ao[(size_t)(b*NN + n0 + w*32 + rt*16 + l15)*CC + kb*32 + quad*8];
    for (int i = tid; i < 2048; i += 256) {
        int row = i >> 4, s8 = i & 15;
        const float* wp = Wp + row*128 + s8*8;
        bf16x8 v;
        #pragma unroll
        for (int j = 0; j < 8; j++) v[j] = (bf16_t)wp[j];
        *(bf16x8*)&wb[row*LDP + s8*8] = v;
    }
    __syncthreads();
    f32x4 acc[2][8];
    f32x4 z = {0.f, 0.f, 0.f, 0.f};
    #pragma unroll
    for (int rt = 0; rt < 2; rt++)
        #pragma unroll
        for (int t = 0; t < 8; t++) acc[rt][t] = z;
    #pragma unroll
    for (int kb = 0; kb < 4; kb++)
        #pragma unroll
        for (int t = 0; t < 8; t++) {
            bf16x8 bf = *(const bf16x8*)&wb[(t*16 + l15)*LDP + kb*32 + quad*8];
            acc[0][t] = mfma16(afr[0][kb], bf, acc[0][t]);
            acc[1][t] = mfma16(afr[1][kb], bf, acc[1][t]);
        }
    __syncthreads();
    #pragma unroll
    for (int t = 0; t < 8; t++) {
        float bias = bp[t*16 + l15];
        #pragma unroll
        for (int rt = 0; rt < 2; rt++)
            #pragma unroll
            for (int r = 0; r < 4; r++) {
                int nloc = w*32 + rt*16 + quad*4 + r;
                wb[(t*16 + l15)*LDP + nloc] = (bf16_t)(acc[rt][t][r] + bias);
            }
    }
    __syncthreads();
    for (int i = tid; i < 8192; i += 256) {
        int c = i >> 6, np = i & 63;
        bf16_t b0 = wb[c*LDP + np*2], b1 = wb[c*LDP + np*2 + 1];
        size_t idx = (size_t)(b*CC + c)*NN + n0 + np*2;
        float2 nv = *(float2*)&out[idx];
        nv.x += (float)b0;
        nv.y += (float)b1;
        *(float2*)&out[idx] = nv;
    }
}

extern "C" void kernel_launch(void* const* d_in, const int* in_sizes, int n_in,
                              void* d_out, int out_size, void* d_ws, size_t ws_size,
                              hipStream_t stream) {
    const float* in = (const float*)d_in[0];
    const float* gw = (const float*)d_in[1];
    const float* gb = (const float*)d_in[2];
    const float* Wq = (const float*)d_in[3];
    const float* bq = (const float*)d_in[4];
    const float* Wk = (const float*)d_in[5];
    const float* bk = (const float*)d_in[6];
    const float* Wv = (const float*)d_in[7];
    const float* bv = (const float*)d_in[8];
    const float* Wp = (const float*)d_in[9];
    const float* bp = (const float*)d_in[10];
    float* out = (float*)d_out;

    char* ws = (char*)d_ws;
    const size_t SZ = (size_t)BB * NN * CC * 2;
    float*  stats = (float*)ws;
    bf16_t* x  = (bf16_t*)(ws + 2048);
    bf16_t* q  = (bf16_t*)(ws + 2048 + SZ);
    bf16_t* kk = (bf16_t*)(ws + 2048 + 2*SZ);
    bf16_t* vT = (bf16_t*)(ws + 2048 + 3*SZ);
    bf16_t* ao = (bf16_t*)(ws + 2048 + 4*SZ);

    gn_stats  <<<256, 256, 0, stream>>>(in, stats);
    gn_apply  <<<512, 256, 0, stream>>>(in, gw, gb, stats, out, x);
    qkv_gemm  <<<256, 256, 0, stream>>>(x, Wq, bq, Wk, bk, Wv, bv, q, kk, vT);
    flash_attn<<<256, 256, 0, stream>>>(q, kk, vT, ao);
    proj_out  <<<256, 256, 0, stream>>>(ao, Wp, bp, out);
}

// Round 4
// 235.230 us; speedup vs baseline: 1.3525x; 1.0145x over previous
//
#include <hip/hip_runtime.h>
#include <hip/hip_bf16.h>
#include <math.h>

typedef __bf16 bf16_t;
typedef __bf16 bf16x8 __attribute__((ext_vector_type(8)));
typedef float  f32x4  __attribute__((ext_vector_type(4)));
typedef float  f32x16 __attribute__((ext_vector_type(16)));

#define BB 8
#define CC 128
#define NN 4096
#define LDP 136
// 1/sqrt(128) * log2(e)  (attention scale folded into q, softmax in exp2 domain)
#define SCALE2 0.12751743342f

static __device__ __forceinline__ f32x4 mfma16(bf16x8 a, bf16x8 b, f32x4 c) {
    return __builtin_amdgcn_mfma_f32_16x16x32_bf16(a, b, c, 0, 0, 0);
}
static __device__ __forceinline__ f32x16 mfma32(bf16x8 a, bf16x8 b, f32x16 c) {
    return __builtin_amdgcn_mfma_f32_32x32x16_bf16(a, b, c, 0, 0, 0);
}
static __device__ __forceinline__ void gld16(const void* g, void* l) {
    __builtin_amdgcn_global_load_lds(
        (const __attribute__((address_space(1))) void*)g,
        (__attribute__((address_space(3))) void*)l, 16, 0, 0);
}
static __device__ __forceinline__ unsigned pack2bf(float a, float b) {
    union { bf16_t h[2]; unsigned u; } r;
    r.h[0] = (bf16_t)a; r.h[1] = (bf16_t)b;
    return r.u;
}

// ---------------- K1a: GroupNorm stats ----------------
__global__ void __launch_bounds__(256) gn_stats(const float* __restrict__ in,
                                                float* __restrict__ stats) {
    int bg = blockIdx.x;
    const float4* p4 = (const float4*)(in + (size_t)bg * 16384);
    int tid = threadIdx.x;
    float s = 0.f, ss = 0.f;
    for (int i = tid; i < 4096; i += 256) {
        float4 v = p4[i];
        s  += v.x + v.y + v.z + v.w;
        ss += v.x*v.x + v.y*v.y + v.z*v.z + v.w*v.w;
    }
    for (int off = 1; off < 64; off <<= 1) {
        s  += __shfl_xor(s,  off, 64);
        ss += __shfl_xor(ss, off, 64);
    }
    __shared__ float red[8];
    int wv = tid >> 6;
    if ((tid & 63) == 0) { red[wv*2] = s; red[wv*2+1] = ss; }
    __syncthreads();
    if (tid == 0) {
        float S  = red[0]+red[2]+red[4]+red[6];
        float SS = red[1]+red[3]+red[5]+red[7];
        float mu  = S * (1.f/16384.f);
        float var = SS * (1.f/16384.f) - mu*mu;
        stats[bg*2]   = mu;
        stats[bg*2+1] = rsqrtf(var + 1e-5f);
    }
}

// ---------------- K1b: normalize -> d_out (fp32) + x tokens (bf16 [B,N,C]) ----------------
__global__ void __launch_bounds__(256) gn_apply(const float* __restrict__ in,
                                                const float* __restrict__ gw,
                                                const float* __restrict__ gb,
                                                const float* __restrict__ stats,
                                                float* __restrict__ normed,
                                                bf16_t* __restrict__ x) {
    int b  = blockIdx.x >> 6;
    int p0 = (blockIdx.x & 63) << 6;
    int tid = threadIdx.x;
    __shared__ bf16_t tile[64 * 130];
    for (int i = tid; i < 8192; i += 256) {
        int c = i >> 6, p = i & 63;
        size_t idx = ((size_t)(b*CC + c)) * NN + p0 + p;
        float v = in[idx];
        int sg = b*32 + (c >> 2);
        float xn = (v - stats[sg*2]) * stats[sg*2+1] * gw[c] + gb[c];
        normed[idx] = xn;
        tile[p*130 + c] = (bf16_t)xn;
    }
    __syncthreads();
    bf16_t* xb = x + ((size_t)(b*NN + p0)) * CC;
    for (int i = tid; i < 4096; i += 256) {
        int p = i >> 6, cp = i & 63;
        unsigned int d = *(const unsigned int*)&tile[p*130 + cp*2];
        *(unsigned int*)&xb[p*CC + cp*2] = d;
    }
}

// ---------------- K2: q (scaled), k (XOR-swizzled), vT (transposed + bit2<->3 perm + XOR-swizzled) ----
__global__ void __launch_bounds__(256) qkv_gemm(const bf16_t* __restrict__ x,
        const float* __restrict__ Wq, const float* __restrict__ bq,
        const float* __restrict__ Wk, const float* __restrict__ bk,
        const float* __restrict__ Wv, const float* __restrict__ bv,
        bf16_t* __restrict__ q, bf16_t* __restrict__ k, bf16_t* __restrict__ vT) {
    __shared__ bf16_t wb[CC * LDP];
    int b  = blockIdx.x >> 5;
    int n0 = (blockIdx.x & 31) << 7;
    int tid = threadIdx.x;
    int lane = tid & 63, l15 = lane & 15, quad = lane >> 4;
    int w = tid >> 6;
    bf16x8 afr[2][4];
    #pragma unroll
    for (int rt = 0; rt < 2; rt++)
        #pragma unroll
        for (int kb = 0; kb < 4; kb++)
            afr[rt][kb] = *(const bf16x8*)&x[(size_t)(b*NN + n0 + w*32 + rt*16 + l15)*CC + kb*32 + quad*8];

    const float* Ws[3] = {Wq, Wk, Wv};
    const float* bs[3] = {bq, bk, bv};
    for (int ph = 0; ph < 3; ph++) {
        __syncthreads();
        for (int i = tid; i < 2048; i += 256) {
            int row = i >> 4, s8 = i & 15;
            const float* wp = Ws[ph] + row*128 + s8*8;
            bf16x8 v;
            #pragma unroll
            for (int j = 0; j < 8; j++) v[j] = (bf16_t)wp[j];
            *(bf16x8*)&wb[row*LDP + s8*8] = v;
        }
        __syncthreads();
        f32x4 acc[2][8];
        f32x4 z = {0.f, 0.f, 0.f, 0.f};
        #pragma unroll
        for (int rt = 0; rt < 2; rt++)
            #pragma unroll
            for (int t = 0; t < 8; t++) acc[rt][t] = z;
        #pragma unroll
        for (int kb = 0; kb < 4; kb++)
            #pragma unroll
            for (int t = 0; t < 8; t++) {
                bf16x8 bf = *(const bf16x8*)&wb[(t*16 + l15)*LDP + kb*32 + quad*8];
                acc[0][t] = mfma16(afr[0][kb], bf, acc[0][t]);
                acc[1][t] = mfma16(afr[1][kb], bf, acc[1][t]);
            }
        __syncthreads();   // all waves done reading W from wb
        if (ph < 2) {
            float sc = (ph == 0) ? SCALE2 : 1.0f;
            #pragma unroll
            for (int t = 0; t < 8; t++) {
                float bias = bs[ph][t*16 + l15];
                #pragma unroll
                for (int rt = 0; rt < 2; rt++)
                    #pragma unroll
                    for (int r = 0; r < 4; r++) {
                        int nloc = w*32 + rt*16 + quad*4 + r;
                        wb[nloc*LDP + t*16 + l15] = (bf16_t)((acc[rt][t][r] + bias) * sc);
                    }
            }
            __syncthreads();
            bf16_t* outp = (ph == 0) ? q : k;
            for (int i = tid; i < 2048; i += 256) {
                int row = i >> 4, g = i & 15;
                bf16x8 vv = *(const bf16x8*)&wb[row*LDP + g*8];
                int gd = (ph == 0) ? g : (g ^ (row & 15));
                *(bf16x8*)&outp[(size_t)(b*NN + n0 + row)*CC + gd*8] = vv;
            }
        } else {
            #pragma unroll
            for (int t = 0; t < 8; t++) {
                float bias = bs[2][t*16 + l15];
                #pragma unroll
                for (int rt = 0; rt < 2; rt++)
                    #pragma unroll
                    for (int r = 0; r < 4; r++) {
                        int nloc = w*32 + rt*16 + quad*4 + r;   // vT transpose: [c][nloc]
                        wb[(t*16 + l15)*LDP + nloc] = (bf16_t)(acc[rt][t][r] + bias);
                    }
            }
            __syncthreads();
            for (int i = tid; i < 8192; i += 256) {
                int c = i >> 6, np = i & 63;   // np = pair index (n = 2*np)
                unsigned int d = *(const unsigned int*)&wb[c*LDP + np*2];
                // bit2<->3 swap of n == bit1<->2 swap of np (PV B-frag identity perm)
                int npp = (np & ~6) | ((np & 2) << 1) | ((np & 4) >> 1);
                int g = (npp >> 2) ^ (c & 15);            // XOR bank swizzle on 8-elem groups
                *(unsigned int*)&vT[(size_t)(b*CC + c)*NN + n0 + (g << 3) + ((npp & 3) << 1)] = d;
            }
        }
    }
}

// ---------------- K3: flash attention, 64 q-rows/wave (2x frag reuse), j-split halves ----------------
// grid 256: b = blk>>5, qb = (blk>>1)&15 (256 q-rows), jh = blk&1 (2048 j).
// Outputs UNNORMALIZED partial O^T (fp32, [part][b][c][q]) + per-row (m,l).
__global__ void __launch_bounds__(256, 1) flash_attn(const bf16_t* __restrict__ qg_,
                                                     const bf16_t* __restrict__ kg,
                                                     const bf16_t* __restrict__ vg,
                                                     float* __restrict__ opart,
                                                     float* __restrict__ mlb) {
    __shared__ bf16_t kbuf[2][128*128];
    __shared__ bf16_t vbuf[2][128*128];
    const int b    = blockIdx.x >> 5;
    const int qb   = (blockIdx.x >> 1) & 15;
    const int jh   = blockIdx.x & 1;
    const int q0   = qb << 8;
    const int j00  = jh << 11;
    const int tid  = threadIdx.x;
    const int lane = tid & 63;
    const int l31  = lane & 31;
    const int h    = lane >> 5;
    const int w    = tid >> 6;

    // two q-groups per wave: rows q0 + w*64 + qg*32 + l31
    bf16x8 qf0[8], qf1[8];
    {
        const bf16_t* qr0 = qg_ + ((size_t)(b*NN + q0 + w*64 + l31))*CC + h*8;
        const bf16_t* qr1 = qr0 + 32*CC;
        #pragma unroll
        for (int kc = 0; kc < 8; kc++) {
            qf0[kc] = *(const bf16x8*)(qr0 + kc*16);
            qf1[kc] = *(const bf16x8*)(qr1 + kc*16);
        }
    }
    int gofs[8];
    #pragma unroll
    for (int kc = 0; kc < 8; kc++) gofs[kc] = ((2*kc + h) ^ (l31 & 15)) << 3;

    f32x16 ot0[4], ot1[4];
    #pragma unroll
    for (int ct = 0; ct < 4; ct++)
        #pragma unroll
        for (int r = 0; r < 16; r++) { ot0[ct][r] = 0.f; ot1[ct][r] = 0.f; }
    float m0 = -3.0e38f, l0 = 0.f, m1 = -3.0e38f, l1 = 0.f;

    // stage tile 0
    {
        const bf16_t* kt = kg + ((size_t)(b*NN + j00))*CC;
        #pragma unroll
        for (int it = 0; it < 8; it++) {
            int cb = it*256 + w*64;
            gld16(kt + (size_t)(cb + lane)*8, &kbuf[0][cb*8]);
        }
        #pragma unroll
        for (int it = 0; it < 8; it++) {
            int cb = it*256 + w*64;
            int c = cb + lane;
            gld16(vg + ((size_t)(b*CC + (c >> 4)))*NN + j00 + (c & 15)*8, &vbuf[0][cb*8]);
        }
    }
    __syncthreads();

    for (int i = 0; i < 16; i++) {
        const int cur = i & 1;
        if (i < 15) {
            const int j0n = j00 + ((i + 1) << 7);
            const bf16_t* kt = kg + ((size_t)(b*NN + j0n))*CC;
            #pragma unroll
            for (int it = 0; it < 8; it++) {
                int cb = it*256 + w*64;
                gld16(kt + (size_t)(cb + lane)*8, &kbuf[cur^1][cb*8]);
            }
            #pragma unroll
            for (int it = 0; it < 8; it++) {
                int cb = it*256 + w*64;
                int c = cb + lane;
                gld16(vg + ((size_t)(b*CC + (c >> 4)))*NN + j0n + (c & 15)*8, &vbuf[cur^1][cb*8]);
            }
        }
        // S^T = K_tile . Q^T for both q-groups; each kf read feeds 2 MFMAs
        f32x16 st0[4], st1[4];
        #pragma unroll
        for (int tt = 0; tt < 4; tt++)
            #pragma unroll
            for (int r = 0; r < 16; r++) { st0[tt][r] = 0.f; st1[tt][r] = 0.f; }
        #pragma unroll
        for (int tt = 0; tt < 4; tt++) {
            const bf16_t* krow = &kbuf[cur][(tt*32 + l31)*128];
            #pragma unroll
            for (int kc = 0; kc < 8; kc++) {
                bf16x8 kf = *(const bf16x8*)(krow + gofs[kc]);
                st0[tt] = mfma32(kf, qf0[kc], st0[tt]);
                st1[tt] = mfma32(kf, qf1[kc], st1[tt]);
            }
        }
        // ---- softmax qg0 ----
        union { unsigned u[4]; bf16x8 v; } pf0[8], pf1[8];
        {
            float mtt[4];
            #pragma unroll
            for (int tt = 0; tt < 4; tt++) {
                float b0 = fmaxf(fmaxf(st0[tt][0],  st0[tt][1]),  fmaxf(st0[tt][2],  st0[tt][3]));
                float b1 = fmaxf(fmaxf(st0[tt][4],  st0[tt][5]),  fmaxf(st0[tt][6],  st0[tt][7]));
                float b2 = fmaxf(fmaxf(st0[tt][8],  st0[tt][9]),  fmaxf(st0[tt][10], st0[tt][11]));
                float b3 = fmaxf(fmaxf(st0[tt][12], st0[tt][13]), fmaxf(st0[tt][14], st0[tt][15]));
                mtt[tt] = fmaxf(fmaxf(b0, b1), fmaxf(b2, b3));
            }
            float mx = fmaxf(fmaxf(mtt[0], mtt[1]), fmaxf(mtt[2], mtt[3]));
            mx = fmaxf(mx, __shfl_xor(mx, 32, 64));
            float mn = fmaxf(m0, mx);
            float al = __builtin_amdgcn_exp2f(m0 - mn);
            m0 = mn;
            float stt[4];
            #pragma unroll
            for (int tt = 0; tt < 4; tt++) {
                #pragma unroll
                for (int r = 0; r < 16; r++)
                    st0[tt][r] = __builtin_amdgcn_exp2f(st0[tt][r] - mn);
                float b0 = (st0[tt][0]  + st0[tt][1])  + (st0[tt][2]  + st0[tt][3]);
                float b1 = (st0[tt][4]  + st0[tt][5])  + (st0[tt][6]  + st0[tt][7]);
                float b2 = (st0[tt][8]  + st0[tt][9])  + (st0[tt][10] + st0[tt][11]);
                float b3 = (st0[tt][12] + st0[tt][13]) + (st0[tt][14] + st0[tt][15]);
                stt[tt] = (b0 + b1) + (b2 + b3);
            }
            float sum = (stt[0] + stt[1]) + (stt[2] + stt[3]);
            sum += __shfl_xor(sum, 32, 64);
            l0 = l0 * al + sum;
            #pragma unroll
            for (int ct = 0; ct < 4; ct++)
                #pragma unroll
                for (int r = 0; r < 16; r++) ot0[ct][r] *= al;
            #pragma unroll
            for (int tt = 0; tt < 4; tt++)
                #pragma unroll
                for (int kcl = 0; kcl < 2; kcl++)
                    #pragma unroll
                    for (int g = 0; g < 4; g++)
                        pf0[tt*2 + kcl].u[g] = pack2bf(st0[tt][8*kcl + 2*g], st0[tt][8*kcl + 2*g + 1]);
        }
        // ---- softmax qg1 ----
        {
            float mtt[4];
            #pragma unroll
            for (int tt = 0; tt < 4; tt++) {
                float b0 = fmaxf(fmaxf(st1[tt][0],  st1[tt][1]),  fmaxf(st1[tt][2],  st1[tt][3]));
                float b1 = fmaxf(fmaxf(st1[tt][4],  st1[tt][5]),  fmaxf(st1[tt][6],  st1[tt][7]));
                float b2 = fmaxf(fmaxf(st1[tt][8],  st1[tt][9]),  fmaxf(st1[tt][10], st1[tt][11]));
                float b3 = fmaxf(fmaxf(st1[tt][12], st1[tt][13]), fmaxf(st1[tt][14], st1[tt][15]));
                mtt[tt] = fmaxf(fmaxf(b0, b1), fmaxf(b2, b3));
            }
            float mx = fmaxf(fmaxf(mtt[0], mtt[1]), fmaxf(mtt[2], mtt[3]));
            mx = fmaxf(mx, __shfl_xor(mx, 32, 64));
            float mn = fmaxf(m1, mx);
            float al = __builtin_amdgcn_exp2f(m1 - mn);
            m1 = mn;
            float stt[4];
            #pragma unroll
            for (int tt = 0; tt < 4; tt++) {
                #pragma unroll
                for (int r = 0; r < 16; r++)
                    st1[tt][r] = __builtin_amdgcn_exp2f(st1[tt][r] - mn);
                float b0 = (st1[tt][0]  + st1[tt][1])  + (st1[tt][2]  + st1[tt][3]);
                float b1 = (st1[tt][4]  + st1[tt][5])  + (st1[tt][6]  + st1[tt][7]);
                float b2 = (st1[tt][8]  + st1[tt][9])  + (st1[tt][10] + st1[tt][11]);
                float b3 = (st1[tt][12] + st1[tt][13]) + (st1[tt][14] + st1[tt][15]);
                stt[tt] = (b0 + b1) + (b2 + b3);
            }
            float sum = (stt[0] + stt[1]) + (stt[2] + stt[3]);
            sum += __shfl_xor(sum, 32, 64);
            l1 = l1 * al + sum;
            #pragma unroll
            for (int ct = 0; ct < 4; ct++)
                #pragma unroll
                for (int r = 0; r < 16; r++) ot1[ct][r] *= al;
            #pragma unroll
            for (int tt = 0; tt < 4; tt++)
                #pragma unroll
                for (int kcl = 0; kcl < 2; kcl++)
                    #pragma unroll
                    for (int g = 0; g < 4; g++)
                        pf1[tt*2 + kcl].u[g] = pack2bf(st1[tt][8*kcl + 2*g], st1[tt][8*kcl + 2*g + 1]);
        }
        // O^T += V^T . P^T — each vf read feeds 2 MFMAs
        #pragma unroll
        for (int tt = 0; tt < 4; tt++)
            #pragma unroll
            for (int kcl = 0; kcl < 2; kcl++) {
                const int kc = tt*2 + kcl;
                #pragma unroll
                for (int ct = 0; ct < 4; ct++) {
                    bf16x8 vf = *(const bf16x8*)&vbuf[cur][(ct*32 + l31)*128 + gofs[kc]];
                    ot0[ct] = mfma32(vf, pf0[kc].v, ot0[ct]);
                    ot1[ct] = mfma32(vf, pf1[kc].v, ot1[ct]);
                }
            }
        __syncthreads();
    }
    // epilogue: unnormalized partials, [part][b][chan][q] fp32 + (m,l) per row
    {
        const int qrow0 = q0 + w*64 + l31;
        float* ob = opart + ((size_t)(jh*BB + b) * CC) * NN;
        #pragma unroll
        for (int ct = 0; ct < 4; ct++)
            #pragma unroll
            for (int r = 0; r < 16; r++) {
                int chan = ct*32 + (r & 3) + ((r >> 2) << 3) + 4*h;
                ob[(size_t)chan * NN + qrow0]      = ot0[ct][r];
                ob[(size_t)chan * NN + qrow0 + 32] = ot1[ct][r];
            }
        if (h == 0) {
            float2* mlp = (float2*)mlb + ((size_t)(jh*BB + b)) * NN;
            mlp[qrow0]      = make_float2(m0, l0);
            mlp[qrow0 + 32] = make_float2(m1, l1);
        }
    }
}

// ---------------- K3b: merge the two j-half partials -> ao (bf16 [B,N,C]) ----------------
__global__ void __launch_bounds__(256) merge_attn(const float* __restrict__ opart,
                                                  const float* __restrict__ mlb,
                                                  bf16_t* __restrict__ ao) {
    __shared__ float wts[2][128];
    __shared__ bf16_t tile[128*136];
    const int b  = blockIdx.x >> 5;
    const int q0 = (blockIdx.x & 31) << 7;
    const int tid = threadIdx.x;
    if (tid < 128) {
        const float2* mlp = (const float2*)mlb;
        float2 a = mlp[(size_t)b*NN + q0 + tid];
        float2 c = mlp[(size_t)(BB + b)*NN + q0 + tid];
        float mm = fmaxf(a.x, c.x);
        float e1 = __builtin_amdgcn_exp2f(a.x - mm);
        float e2 = __builtin_amdgcn_exp2f(c.x - mm);
        float inv = 1.0f / (a.y*e1 + c.y*e2);
        wts[0][tid] = e1 * inv;
        wts[1][tid] = e2 * inv;
    }
    __syncthreads();
    const float* o1 = opart + ((size_t)b * CC) * NN + q0;
    const float* o2 = opart + ((size_t)(BB + b) * CC) * NN + q0;
    for (int i = tid; i < 16384; i += 256) {
        int c = i >> 7, qi = i & 127;
        float v = o1[(size_t)c*NN + qi] * wts[0][qi] + o2[(size_t)c*NN + qi] * wts[1][qi];
        tile[qi*136 + c] = (bf16_t)v;
    }
    __syncthreads();
    for (int i = tid; i < 2048; i += 256) {
        int qi = i >> 4, g = i & 15;
        *(bf16x8*)&ao[((size_t)(b*NN + q0 + qi))*CC + g*8] = *(bf16x8*)&tile[qi*136 + g*8];
    }
}

// ---------------- K4: proj GEMM + bias + transpose + residual into d_out ----------------
__global__ void __launch_bounds__(256) proj_out(const bf16_t* __restrict__ ao,
                                                const float* __restrict__ Wp,
                                                const float* __restrict__ bp,
                                                float* __restrict__ out) {
    __shared__ bf16_t wb[CC * LDP];
    int b  = blockIdx.x >> 5;
    int n0 = (blockIdx.x & 31) << 7;
    int tid = threadIdx.x;
    int lane = tid & 63, l15 = lane & 15, quad = lane >> 4;
    int w = tid >> 6;
    bf16x8 afr[2][4];
    #pragma unroll
    for (int rt = 0; rt < 2; rt++)
        #pragma unroll
        for (int kb = 0; kb < 4; kb++)
            afr[rt][kb] = *(const bf16x8*)&ao[(size_t)(b*NN + n0 + w*32 + rt*16 + l15)*CC + kb*32 + quad*8];
    for (int i = tid; i < 2048; i += 256) {
        int row = i >> 4, s8 = i & 15;
        const float* wp = Wp + row*128 + s8*8;
        bf16x8 v;
        #pragma unroll
        for (int j = 0; j < 8; j++) v[j] = (bf16_t)wp[j];
        *(bf16x8*)&wb[row*LDP + s8*8] = v;
    }
    __syncthreads();
    f32x4 acc[2][8];
    f32x4 z = {0.f, 0.f, 0.f, 0.f};
    #pragma unroll
    for (int rt = 0; rt < 2; rt++)
        #pragma unroll
        for (int t = 0; t < 8; t++) acc[rt][t] = z;
    #pragma unroll
    for (int kb = 0; kb < 4; kb++)
        #pragma unroll
        for (int t = 0; t < 8; t++) {
            bf16x8 bf = *(const bf16x8*)&wb[(t*16 + l15)*LDP + kb*32 + quad*8];
            acc[0][t] = mfma16(afr[0][kb], bf, acc[0][t]);
            acc[1][t] = mfma16(afr[1][kb], bf, acc[1][t]);
        }
    __syncthreads();
    #pragma unroll
    for (int t = 0; t < 8; t++) {
        float bias = bp[t*16 + l15];
        #pragma unroll
        for (int rt = 0; rt < 2; rt++)
            #pragma unroll
            for (int r = 0; r < 4; r++) {
                int nloc = w*32 + rt*16 + quad*4 + r;
                wb[(t*16 + l15)*LDP + nloc] = (bf16_t)(acc[rt][t][r] + bias);
            }
    }
    __syncthreads();
    for (int i = tid; i < 8192; i += 256) {
        int c = i >> 6, np = i & 63;
        bf16_t b0 = wb[c*LDP + np*2], b1 = wb[c*LDP + np*2 + 1];
        size_t idx = (size_t)(b*CC + c)*NN + n0 + np*2;
        float2 nv = *(float2*)&out[idx];
        nv.x += (float)b0;
        nv.y += (float)b1;
        *(float2*)&out[idx] = nv;
    }
}

extern "C" void kernel_launch(void* const* d_in, const int* in_sizes, int n_in,
                              void* d_out, int out_size, void* d_ws, size_t ws_size,
                              hipStream_t stream) {
    const float* in = (const float*)d_in[0];
    const float* gw = (const float*)d_in[1];
    const float* gb = (const float*)d_in[2];
    const float* Wq = (const float*)d_in[3];
    const float* bq = (const float*)d_in[4];
    const float* Wk = (const float*)d_in[5];
    const float* bk = (const float*)d_in[6];
    const float* Wv = (const float*)d_in[7];
    const float* bv = (const float*)d_in[8];
    const float* Wp = (const float*)d_in[9];
    const float* bp = (const float*)d_in[10];
    float* out = (float*)d_out;

    char* ws = (char*)d_ws;
    const size_t SZ = (size_t)BB * NN * CC * 2;        // 8.39 MB
    float*  stats = (float*)ws;
    bf16_t* x  = (bf16_t*)(ws + 2048);
    bf16_t* q  = (bf16_t*)(ws + 2048 + SZ);
    bf16_t* kk = (bf16_t*)(ws + 2048 + 2*SZ);
    bf16_t* vT = (bf16_t*)(ws + 2048 + 3*SZ);
    bf16_t* ao = (bf16_t*)(ws + 2048 + 4*SZ);
    float*  op = (float*)(ws + 2048 + 5*SZ);           // 33.55 MB partials
    float*  ml = (float*)(ws + 2048 + 5*SZ + (size_t)2*BB*CC*NN*4);

    gn_stats  <<<256, 256, 0, stream>>>(in, stats);
    gn_apply  <<<512, 256, 0, stream>>>(in, gw, gb, stats, out, x);
    qkv_gemm  <<<256, 256, 0, stream>>>(x, Wq, bq, Wk, bk, Wv, bv, q, kk, vT);
    flash_attn<<<256, 256, 0, stream>>>(q, kk, vT, op, ml);
    merge_attn<<<256, 256, 0, stream>>>(op, ml, ao);
    proj_out  <<<256, 256, 0, stream>>>(ao, Wp, bp, out);
}